// Round 2
// baseline (2658.639 us; speedup 1.0000x reference)
//
#include <hip/hip_runtime.h>
#include <stdint.h>

#define BB 512
#define TT 1000
#define CC 64
#define HH 128
#define TDA_F 150
#define NCLS 4
#define EPSV 1e-5f
#define CHUNK 8
#define NSEG 8
#define SEGLEN 125   // TT / NSEG
#define WARM 51      // uncounted warm-up steps; SEGLEN+WARM = 176 = 22*CHUNK

// Async global->LDS stage of one chunk (8 steps x 64 floats = 2048 B) via two
// 1 KB global_load_lds ops (16 B/lane, lds dest = uniform base + lane*16).
__device__ __forceinline__ void stage_chunk(const float* __restrict__ g,
                                            float* lbase, int lane) {
  __builtin_amdgcn_global_load_lds(
      (const __attribute__((address_space(1))) void*)(g + lane * 4),
      (__attribute__((address_space(3))) void*)(lbase), 16, 0, 0);
  __builtin_amdgcn_global_load_lds(
      (const __attribute__((address_space(1))) void*)(g + 256 + lane * 4),
      (__attribute__((address_space(3))) void*)(lbase + 256), 16, 0, 0);
}

// ---------------------------------------------------------------------------
// Fused current-GEMM + LIF scan, T-segmented for occupancy.
// Grid: 512 b x 8 segments; block = 64 threads (1 wave). Lane j owns h=j and
// h=j+64 (G=2: w rows in 128 VGPRs). kin staged through 3 LDS buffers with
// global_load_lds + manual vmcnt waits -- no barriers (single-wave block).
// Segments s>=1 run WARM uncounted warm-up steps; reset-to-zero coalescence
// makes the counted window near-exact (threshold 19.28 gives huge slack).
// ---------------------------------------------------------------------------
__global__ __launch_bounds__(64, 3) void snn_scan(
    const float* __restrict__ kin, const float* __restrict__ Wfc,
    const float* __restrict__ bfc, float* __restrict__ counts)
{
  const int lane = threadIdx.x;
  const int b = blockIdx.x >> 3;
  const int seg = blockIdx.x & 7;

  const int t0 = (seg == 0) ? 0 : SEGLEN * seg - WARM;
  const int nch = (seg == 0) ? 16 : 22;  // 128 or 176 steps
  const int lo = SEGLEN * seg;
  const int hi = lo + SEGLEN;

  // Two W_fc rows -> 128 VGPRs.
  float w0[CC], w1[CC];
  const float4* wr0 = (const float4*)(Wfc + lane * CC);
  const float4* wr1 = (const float4*)(Wfc + (lane + 64) * CC);
#pragma unroll
  for (int i = 0; i < CC / 4; ++i) {
    float4 v0 = wr0[i], v1 = wr1[i];
    w0[4 * i + 0] = v0.x; w0[4 * i + 1] = v0.y;
    w0[4 * i + 2] = v0.z; w0[4 * i + 3] = v0.w;
    w1[4 * i + 0] = v1.x; w1[4 * i + 1] = v1.y;
    w1[4 * i + 2] = v1.z; w1[4 * i + 3] = v1.w;
  }
  const float bias0 = bfc[lane], bias1 = bfc[lane + 64];

  __shared__ float kbuf[3][CHUNK * CC];  // 3 x 2 KB
  const float* gbase = kin + ((size_t)b * TT + t0) * CC;

  stage_chunk(gbase, kbuf[0], lane);
  stage_chunk(gbase + 1 * CHUNK * CC, kbuf[1], lane);

  float mem0 = 0.f, mem1 = 0.f, cnt0 = 0.f, cnt1 = 0.f;

  for (int c = 0; c < nch; ++c) {
    const bool more2 = (c + 2 < nch);
    if (more2) stage_chunk(gbase + (size_t)(c + 2) * CHUNK * CC,
                           kbuf[(c + 2) % 3], lane);
    // Wait for chunk c's two loads (FIFO vmcnt), keep later chunks in flight.
    if (more2)            asm volatile("s_waitcnt vmcnt(4)" ::: "memory");
    else if (c + 1 < nch) asm volatile("s_waitcnt vmcnt(2)" ::: "memory");
    else                  asm volatile("s_waitcnt vmcnt(0)" ::: "memory");

    const float* buf = kbuf[c % 3];
    const int tb = t0 + c * CHUNK;
#pragma unroll
    for (int s = 0; s < CHUNK; ++s) {
      const float4* kr = (const float4*)(buf + s * CC);
      float a0 = bias0, a1 = 0.f, a2 = 0.f, a3 = 0.f;
      float e0 = bias1, e1 = 0.f, e2 = 0.f, e3 = 0.f;
#pragma unroll
      for (int i = 0; i < CC / 4; ++i) {
        float4 k = kr[i];  // uniform address -> LDS broadcast
        a0 = fmaf(k.x, w0[4 * i + 0], a0);
        a1 = fmaf(k.y, w0[4 * i + 1], a1);
        a2 = fmaf(k.z, w0[4 * i + 2], a2);
        a3 = fmaf(k.w, w0[4 * i + 3], a3);
        e0 = fmaf(k.x, w1[4 * i + 0], e0);
        e1 = fmaf(k.y, w1[4 * i + 1], e1);
        e2 = fmaf(k.z, w1[4 * i + 2], e2);
        e3 = fmaf(k.w, w1[4 * i + 3], e3);
      }
      const int t = tb + s;
      const bool act = (t >= lo) && (t < hi);
      const float cur0 = (a0 + a1) + (a2 + a3);
      const float cur1 = (e0 + e1) + (e2 + e3);
      mem0 = fmaf(0.9f, mem0, cur0);
      mem1 = fmaf(0.9f, mem1, cur1);
      const bool s0 = (mem0 >= 1.0f);
      const bool s1 = (mem1 >= 1.0f);
      cnt0 += (act && s0) ? 1.0f : 0.0f;
      cnt1 += (act && s1) ? 1.0f : 0.0f;
      mem0 = s0 ? 0.0f : mem0;
      mem1 = s1 ? 0.0f : mem1;
    }
  }

  atomicAdd(&counts[b * HH + lane], cnt0);
  atomicAdd(&counts[b * HH + lane + 64], cnt1);
}

// ---------------------------------------------------------------------------
// Fused head: tda_net (150->64 relu ->64 relu) + fc1 (192->128) + BN stats.
// One block per sample, 128 threads.
// ---------------------------------------------------------------------------
__global__ __launch_bounds__(HH) void fused_head(
    const float* __restrict__ counts, const float* __restrict__ tda,
    const float* __restrict__ W1, const float* __restrict__ b1,
    const float* __restrict__ W2, const float* __restrict__ b2,
    const float* __restrict__ Wc1, const float* __restrict__ bc1,
    float* __restrict__ hbuf, float* __restrict__ colstats /* [2*128] */)
{
  const int b = blockIdx.x, j = threadIdx.x;
  __shared__ float x[TDA_F];
  __shared__ float h1[64];
  __shared__ float f[HH + 64];

  f[j] = counts[b * HH + j] * (1.0f / TT);
  for (int i = j; i < TDA_F; i += HH) x[i] = tda[b * TDA_F + i];
  __syncthreads();
  if (j < 64) {
    float acc = b1[j];
    const float* wr = W1 + j * TDA_F;
#pragma unroll 5
    for (int i = 0; i < TDA_F; ++i) acc = fmaf(x[i], wr[i], acc);
    h1[j] = fmaxf(acc, 0.0f);
  }
  __syncthreads();
  if (j < 64) {
    float acc = b2[j];
    const float* wr = W2 + j * 64;
#pragma unroll
    for (int i = 0; i < 64; ++i) acc = fmaf(h1[i], wr[i], acc);
    f[HH + j] = fmaxf(acc, 0.0f);
  }
  __syncthreads();
  float acc = bc1[j];
  const float* wr = Wc1 + j * (HH + 64);
#pragma unroll 4
  for (int i = 0; i < HH + 64; ++i) acc = fmaf(f[i], wr[i], acc);
  hbuf[b * HH + j] = acc;
  atomicAdd(&colstats[j], acc);
  atomicAdd(&colstats[HH + j], acc * acc);
}

// ---------------------------------------------------------------------------
// BN (batch stats, biased var) + relu + 128->4 GEMM.
// ---------------------------------------------------------------------------
__global__ __launch_bounds__(HH) void classifier2(
    const float* __restrict__ hbuf, const float* __restrict__ colstats,
    const float* __restrict__ gamma, const float* __restrict__ beta,
    const float* __restrict__ Wc2, const float* __restrict__ bc2,
    float* __restrict__ out)
{
  const int b = blockIdx.x, j = threadIdx.x;
  const float mean = colstats[j] * (1.0f / BB);
  const float ex2 = colstats[HH + j] * (1.0f / BB);
  const float var = ex2 - mean * mean;
  float hn = (hbuf[b * HH + j] - mean) * rsqrtf(var + EPSV) * gamma[j] + beta[j];
  hn = fmaxf(hn, 0.0f);

  __shared__ float red[NCLS][HH];
#pragma unroll
  for (int k = 0; k < NCLS; ++k) red[k][j] = hn * Wc2[k * HH + j];
  __syncthreads();
  for (int off = HH / 2; off >= 1; off >>= 1) {
    if (j < off) {
#pragma unroll
      for (int k = 0; k < NCLS; ++k) red[k][j] += red[k][j + off];
    }
    __syncthreads();
  }
  if (j < NCLS) out[b * NCLS + j] = red[j][0] + bc2[j];
}

// ---------------------------------------------------------------------------
extern "C" void kernel_launch(void* const* d_in, const int* in_sizes, int n_in,
                              void* d_out, int out_size, void* d_ws, size_t ws_size,
                              hipStream_t stream)
{
  const float* kin  = (const float*)d_in[0];   // [512,1000,64]
  const float* tda  = (const float*)d_in[1];   // [512,150]
  const float* Wfc  = (const float*)d_in[2];   // [128,64]
  const float* bfc  = (const float*)d_in[3];   // [128]
  const float* Wt1  = (const float*)d_in[4];   // [64,150]
  const float* bt1  = (const float*)d_in[5];   // [64]
  const float* Wt2  = (const float*)d_in[6];   // [64,64]
  const float* bt2  = (const float*)d_in[7];   // [64]
  const float* Wc1  = (const float*)d_in[8];   // [128,192]
  const float* bc1  = (const float*)d_in[9];   // [128]
  const float* gam  = (const float*)d_in[10];  // [128]
  const float* bet  = (const float*)d_in[11];  // [128]
  const float* Wc2  = (const float*)d_in[12];  // [4,128]
  const float* bc2  = (const float*)d_in[13];  // [4]

  float* out    = (float*)d_out;        // output 0: [512,4]
  float* counts = out + BB * NCLS;      // output 1: [512,128]

  float* hbuf     = (float*)d_ws;               // [512,128]
  float* colstats = hbuf + BB * HH;             // [256]

  hipMemsetAsync(counts, 0, BB * HH * sizeof(float), stream);
  hipMemsetAsync(colstats, 0, 2 * HH * sizeof(float), stream);

  snn_scan<<<BB * NSEG, 64, 0, stream>>>(kin, Wfc, bfc, counts);
  fused_head<<<BB, HH, 0, stream>>>(counts, tda, Wt1, bt1, Wt2, bt2,
                                    Wc1, bc1, hbuf, colstats);
  classifier2<<<BB, HH, 0, stream>>>(hbuf, colstats, gam, bet, Wc2, bc2, out);
}

// Round 3
// 482.996 us; speedup vs baseline: 5.5045x; 5.5045x over previous
//
#include <hip/hip_runtime.h>
#include <stdint.h>

#define BB 512
#define TT 1000
#define CC 64
#define HH 128
#define TDA_F 150
#define NCLS 4
#define EPSV 1e-5f
#define CHUNK 8
#define NSEG 8
#define SEGLEN 125   // TT / NSEG
#define WARM 51      // uncounted warm-up; SEGLEN+WARM = 176 = 22*CHUNK

// Async global->LDS stage of one chunk (8 steps x 64 floats = 2048 B) via two
// 1 KB global_load_lds ops (16 B/lane, lds dest = uniform base + lane*16).
__device__ __forceinline__ void stage_chunk(const float* __restrict__ g,
                                            float* lbase, int lane) {
  __builtin_amdgcn_global_load_lds(
      (const __attribute__((address_space(1))) void*)(g + lane * 4),
      (__attribute__((address_space(3))) void*)(lbase), 16, 0, 0);
  __builtin_amdgcn_global_load_lds(
      (const __attribute__((address_space(1))) void*)(g + 256 + lane * 4),
      (__attribute__((address_space(3))) void*)(lbase + 256), 16, 0, 0);
}

// ---------------------------------------------------------------------------
// Fused current-GEMM + LIF scan, T-segmented for occupancy.
// Grid: 512 b x 8 segments; block = 64 threads (1 wave). Lane j owns h=j and
// h=j+64 (G=2: two W rows = 128 VGPRs -> __launch_bounds__(64,2) caps VGPR at
// 256; (64,3)'s 170-cap forced a catastrophic scratch spill in R2).
// kin staged through 3 LDS buffers with global_load_lds + manual vmcnt waits
// (FIFO retirement makes older stray vmem ops only strengthen the waits).
// Segments s>=1 run WARM uncounted warm-up steps; LIF reset-to-zero
// coalescence makes the counted window near-exact (abs threshold 19.28).
// Per-segment partial counts -> ws (plain stores; summed in fused_head).
// ---------------------------------------------------------------------------
__global__ __launch_bounds__(64, 2) void snn_scan(
    const float* __restrict__ kin, const float* __restrict__ Wfc,
    const float* __restrict__ bfc, float* __restrict__ part,
    float* __restrict__ colstats)
{
  const int lane = threadIdx.x;
  const int b = blockIdx.x >> 3;
  const int seg = blockIdx.x & 7;

  // Block 0 zeroes the BN-stats accumulator (read only by later kernels).
  if (blockIdx.x == 0) {
#pragma unroll
    for (int i = 0; i < 4; ++i) colstats[lane * 4 + i] = 0.0f;
  }

  const int t0 = (seg == 0) ? 0 : SEGLEN * seg - WARM;
  const int nch = (seg == 0) ? 16 : 22;  // 128 or 176 steps
  const int lo = SEGLEN * seg;
  const int hi = lo + SEGLEN;

  // Two W_fc rows -> 128 VGPRs (one-time, L2-served; W_fc is 32 KB).
  float w0[CC], w1[CC];
  const float4* wr0 = (const float4*)(Wfc + lane * CC);
  const float4* wr1 = (const float4*)(Wfc + (lane + 64) * CC);
#pragma unroll
  for (int i = 0; i < CC / 4; ++i) {
    float4 v0 = wr0[i], v1 = wr1[i];
    w0[4 * i + 0] = v0.x; w0[4 * i + 1] = v0.y;
    w0[4 * i + 2] = v0.z; w0[4 * i + 3] = v0.w;
    w1[4 * i + 0] = v1.x; w1[4 * i + 1] = v1.y;
    w1[4 * i + 2] = v1.z; w1[4 * i + 3] = v1.w;
  }
  const float bias0 = bfc[lane], bias1 = bfc[lane + 64];

  __shared__ float kbuf[3][CHUNK * CC];  // 3 x 2 KB
  const float* gbase = kin + ((size_t)b * TT + t0) * CC;

  stage_chunk(gbase, kbuf[0], lane);
  stage_chunk(gbase + 1 * CHUNK * CC, kbuf[1], lane);

  float mem0 = 0.f, mem1 = 0.f, cnt0 = 0.f, cnt1 = 0.f;

  for (int c = 0; c < nch; ++c) {
    const bool more2 = (c + 2 < nch);
    if (more2) stage_chunk(gbase + (size_t)(c + 2) * CHUNK * CC,
                           kbuf[(c + 2) % 3], lane);
    // Wait for chunk c's two loads; keep newer chunks in flight (FIFO vmcnt).
    if (more2)            asm volatile("s_waitcnt vmcnt(4)" ::: "memory");
    else if (c + 1 < nch) asm volatile("s_waitcnt vmcnt(2)" ::: "memory");
    else                  asm volatile("s_waitcnt vmcnt(0)" ::: "memory");

    const float* buf = kbuf[c % 3];
    const int tb = t0 + c * CHUNK;
#pragma unroll
    for (int s = 0; s < CHUNK; ++s) {
      const float4* kr = (const float4*)(buf + s * CC);
      float a0 = bias0, a1 = 0.f, a2 = 0.f, a3 = 0.f;
      float e0 = bias1, e1 = 0.f, e2 = 0.f, e3 = 0.f;
#pragma unroll
      for (int i = 0; i < CC / 4; ++i) {
        float4 k = kr[i];  // uniform address -> LDS broadcast
        a0 = fmaf(k.x, w0[4 * i + 0], a0);
        a1 = fmaf(k.y, w0[4 * i + 1], a1);
        a2 = fmaf(k.z, w0[4 * i + 2], a2);
        a3 = fmaf(k.w, w0[4 * i + 3], a3);
        e0 = fmaf(k.x, w1[4 * i + 0], e0);
        e1 = fmaf(k.y, w1[4 * i + 1], e1);
        e2 = fmaf(k.z, w1[4 * i + 2], e2);
        e3 = fmaf(k.w, w1[4 * i + 3], e3);
      }
      const int t = tb + s;
      const bool act = (t >= lo) && (t < hi);
      const float cur0 = (a0 + a1) + (a2 + a3);
      const float cur1 = (e0 + e1) + (e2 + e3);
      mem0 = fmaf(0.9f, mem0, cur0);
      mem1 = fmaf(0.9f, mem1, cur1);
      const bool s0 = (mem0 >= 1.0f);
      const bool s1 = (mem1 >= 1.0f);
      cnt0 += (act && s0) ? 1.0f : 0.0f;
      cnt1 += (act && s1) ? 1.0f : 0.0f;
      mem0 = s0 ? 0.0f : mem0;
      mem1 = s1 ? 0.0f : mem1;
    }
  }

  float* p = part + ((size_t)(seg * BB + b)) * HH;
  p[lane] = cnt0;
  p[lane + 64] = cnt1;
}

// ---------------------------------------------------------------------------
// Fused head: partial-count reduce + counts output + tda_net
// (150->64 relu ->64 relu) + fc1 (192->128) + BN batch-stat atomics.
// One block per sample, 128 threads.
// ---------------------------------------------------------------------------
__global__ __launch_bounds__(HH) void fused_head(
    const float* __restrict__ part, const float* __restrict__ tda,
    const float* __restrict__ W1, const float* __restrict__ b1,
    const float* __restrict__ W2, const float* __restrict__ b2,
    const float* __restrict__ Wc1, const float* __restrict__ bc1,
    float* __restrict__ counts_out, float* __restrict__ hbuf,
    float* __restrict__ colstats /* [2*128] */)
{
  const int b = blockIdx.x, j = threadIdx.x;
  __shared__ float x[TDA_F];
  __shared__ float h1[64];
  __shared__ float f[HH + 64];

  float c = 0.0f;
#pragma unroll
  for (int s = 0; s < NSEG; ++s) c += part[((size_t)(s * BB + b)) * HH + j];
  counts_out[b * HH + j] = c;
  f[j] = c * (1.0f / TT);
  for (int i = j; i < TDA_F; i += HH) x[i] = tda[b * TDA_F + i];
  __syncthreads();
  if (j < 64) {
    float acc = b1[j];
    const float* wr = W1 + j * TDA_F;
#pragma unroll 5
    for (int i = 0; i < TDA_F; ++i) acc = fmaf(x[i], wr[i], acc);
    h1[j] = fmaxf(acc, 0.0f);
  }
  __syncthreads();
  if (j < 64) {
    float acc = b2[j];
    const float* wr = W2 + j * 64;
#pragma unroll
    for (int i = 0; i < 64; ++i) acc = fmaf(h1[i], wr[i], acc);
    f[HH + j] = fmaxf(acc, 0.0f);
  }
  __syncthreads();
  float acc = bc1[j];
  const float* wr = Wc1 + j * (HH + 64);
#pragma unroll 4
  for (int i = 0; i < HH + 64; ++i) acc = fmaf(f[i], wr[i], acc);
  hbuf[b * HH + j] = acc;
  atomicAdd(&colstats[j], acc);
  atomicAdd(&colstats[HH + j], acc * acc);
}

// ---------------------------------------------------------------------------
// BN (batch stats, biased var) + relu + 128->4 GEMM.
// ---------------------------------------------------------------------------
__global__ __launch_bounds__(HH) void classifier2(
    const float* __restrict__ hbuf, const float* __restrict__ colstats,
    const float* __restrict__ gamma, const float* __restrict__ beta,
    const float* __restrict__ Wc2, const float* __restrict__ bc2,
    float* __restrict__ out)
{
  const int b = blockIdx.x, j = threadIdx.x;
  const float mean = colstats[j] * (1.0f / BB);
  const float ex2 = colstats[HH + j] * (1.0f / BB);
  const float var = ex2 - mean * mean;
  float hn = (hbuf[b * HH + j] - mean) * rsqrtf(var + EPSV) * gamma[j] + beta[j];
  hn = fmaxf(hn, 0.0f);

  __shared__ float red[NCLS][HH];
#pragma unroll
  for (int k = 0; k < NCLS; ++k) red[k][j] = hn * Wc2[k * HH + j];
  __syncthreads();
  for (int off = HH / 2; off >= 1; off >>= 1) {
    if (j < off) {
#pragma unroll
      for (int k = 0; k < NCLS; ++k) red[k][j] += red[k][j + off];
    }
    __syncthreads();
  }
  if (j < NCLS) out[b * NCLS + j] = red[j][0] + bc2[j];
}

// ---------------------------------------------------------------------------
extern "C" void kernel_launch(void* const* d_in, const int* in_sizes, int n_in,
                              void* d_out, int out_size, void* d_ws, size_t ws_size,
                              hipStream_t stream)
{
  const float* kin  = (const float*)d_in[0];   // [512,1000,64]
  const float* tda  = (const float*)d_in[1];   // [512,150]
  const float* Wfc  = (const float*)d_in[2];   // [128,64]
  const float* bfc  = (const float*)d_in[3];   // [128]
  const float* Wt1  = (const float*)d_in[4];   // [64,150]
  const float* bt1  = (const float*)d_in[5];   // [64]
  const float* Wt2  = (const float*)d_in[6];   // [64,64]
  const float* bt2  = (const float*)d_in[7];   // [64]
  const float* Wc1  = (const float*)d_in[8];   // [128,192]
  const float* bc1  = (const float*)d_in[9];   // [128]
  const float* gam  = (const float*)d_in[10];  // [128]
  const float* bet  = (const float*)d_in[11];  // [128]
  const float* Wc2  = (const float*)d_in[12];  // [4,128]
  const float* bc2  = (const float*)d_in[13];  // [4]

  float* out    = (float*)d_out;        // output 0: [512,4]
  float* counts = out + BB * NCLS;      // output 1: [512,128]

  float* part     = (float*)d_ws;               // [8][512][128]  (2 MB)
  float* hbuf     = part + NSEG * BB * HH;      // [512,128]
  float* colstats = hbuf + BB * HH;             // [256]

  snn_scan<<<BB * NSEG, 64, 0, stream>>>(kin, Wfc, bfc, part, colstats);
  fused_head<<<BB, HH, 0, stream>>>(part, tda, Wt1, bt1, Wt2, bt2,
                                    Wc1, bc1, counts, hbuf, colstats);
  classifier2<<<BB, HH, 0, stream>>>(hbuf, colstats, gam, bet, Wc2, bc2, out);
}